// Round 1
// baseline (320.227 us; speedup 1.0000x reference)
//
#include <hip/hip_runtime.h>

typedef __attribute__((ext_vector_type(4))) short short4v;
typedef __attribute__((ext_vector_type(8))) short short8v;
typedef __attribute__((ext_vector_type(4))) float float4v;
typedef __attribute__((ext_vector_type(4))) int int4v;

__device__ __forceinline__ short f2bf(float f) {
    unsigned u = __builtin_bit_cast(unsigned, f);
    u += 0x7fffu + ((u >> 16) & 1u);
    return (short)(u >> 16);
}

// ---------------- x: fp32 -> bf16 (vectorized) ----------------
__global__ void k_cvt_x(const float* __restrict__ x, short* __restrict__ xb) {
    int i = blockIdx.x * blockDim.x + threadIdx.x;   // 4096*256 threads, 4 elems each
    float4v v = ((const float4v*)x)[i];
    short4v o;
    o[0] = f2bf(v[0]); o[1] = f2bf(v[1]); o[2] = f2bf(v[2]); o[3] = f2bf(v[3]);
    ((short4v*)xb)[i] = o;
}

// ---------------- W[k][n] fp32 -> Wt[n][k] bf16 (LDS tile transpose) ----------------
__global__ void k_transpose(const float* __restrict__ W0, const float* __restrict__ W1,
                            const float* __restrict__ W2, const float* __restrict__ W3,
                            short* __restrict__ Wt) {
    const float* W = blockIdx.z == 0 ? W0 : blockIdx.z == 1 ? W1 : blockIdx.z == 2 ? W2 : W3;
    short* dst = Wt + (size_t)blockIdx.z * 1024 * 1024;
    __shared__ float tile[32][33];
    int x0 = blockIdx.x * 32, y0 = blockIdx.y * 32;
    int tx = threadIdx.x, ty = threadIdx.y;
#pragma unroll
    for (int j = 0; j < 4; j++) {
        int r = ty + j * 8;
        tile[r][tx] = W[(size_t)(y0 + r) * 1024 + x0 + tx];
    }
    __syncthreads();
#pragma unroll
    for (int j = 0; j < 4; j++) {
        int r = ty + j * 8;
        dst[(size_t)(x0 + r) * 1024 + y0 + tx] = f2bf(tile[tx][r]);
    }
}

// ---------------- bf16 MFMA GEMM: C[4096x1024] = A[4096x1024] @ Bt[n][k]^T ----------------
// mode 0: blockIdx.z selects Q/K/V weight+output; head-major remap; Q scaled 1/8; V transposed.
// mode 1: plain fp32 output to outF.
__launch_bounds__(256)
__global__ void k_gemm(const short* __restrict__ A, const short* __restrict__ Bt,
                       short* __restrict__ outQ, short* __restrict__ outK,
                       short* __restrict__ outVt, float* __restrict__ outF, int mode) {
    __shared__ short As[128][40];   // 80B rows: 16B-aligned b128 reads
    __shared__ short Bs[128][40];
    int t = threadIdx.x;
    int l = t & 63, w = t >> 6;
    int wr = w >> 1, wc = w & 1;
    int lr = l & 15, lg = l >> 4;
    int m0 = blockIdx.x * 128;
    int n0 = blockIdx.y * 128;
    int which = (mode == 0) ? blockIdx.z : 3;
    const short* Bp = (mode == 0) ? Bt + (size_t)which * 1048576 : Bt;

    float4v acc[4][4] = {};

    for (int k0 = 0; k0 < 1024; k0 += 32) {
#pragma unroll
        for (int i = 0; i < 2; i++) {
            int e = t + i * 256;
            int row = e >> 2, kc = (e & 3) * 8;
            *(int4v*)&As[row][kc] = *(const int4v*)&A[(size_t)(m0 + row) * 1024 + k0 + kc];
            *(int4v*)&Bs[row][kc] = *(const int4v*)&Bp[(size_t)(n0 + row) * 1024 + k0 + kc];
        }
        __syncthreads();
        short8v af[4], bfr[4];
#pragma unroll
        for (int fr = 0; fr < 4; fr++) af[fr] = *(const short8v*)&As[wr * 64 + fr * 16 + lr][lg * 8];
#pragma unroll
        for (int fc = 0; fc < 4; fc++) bfr[fc] = *(const short8v*)&Bs[wc * 64 + fc * 16 + lr][lg * 8];
#pragma unroll
        for (int fr = 0; fr < 4; fr++)
#pragma unroll
            for (int fc = 0; fc < 4; fc++)
                acc[fr][fc] = __builtin_amdgcn_mfma_f32_16x16x32_bf16(af[fr], bfr[fc], acc[fr][fc], 0, 0, 0);
        __syncthreads();
    }

    // epilogue: C/D layout col = lane&15, row = (lane>>4)*4 + r  [m89]
    if (mode == 0) {
        short* out = which == 0 ? outQ : which == 1 ? outK : outVt;
        float scale = (which == 0) ? 0.125f : 1.0f;
#pragma unroll
        for (int fr = 0; fr < 4; fr++)
#pragma unroll
            for (int fc = 0; fc < 4; fc++)
#pragma unroll
                for (int r = 0; r < 4; r++) {
                    int m = m0 + wr * 64 + fr * 16 + lg * 4 + r;
                    int n = n0 + wc * 64 + fc * 16 + lr;
                    float v = acc[fr][fc][r] * scale;
                    int b = m >> 11, s = m & 2047, h = n >> 6, dh = n & 63;
                    if (which < 2)
                        out[(((size_t)(b * 16 + h)) * 2048 + s) * 64 + dh] = f2bf(v);
                    else
                        out[(((size_t)(b * 16 + h)) * 64 + dh) * 2048 + s] = f2bf(v);
                }
    } else {
#pragma unroll
        for (int fr = 0; fr < 4; fr++)
#pragma unroll
            for (int fc = 0; fc < 4; fc++)
#pragma unroll
                for (int r = 0; r < 4; r++) {
                    int m = m0 + wr * 64 + fr * 16 + lg * 4 + r;
                    int n = n0 + wc * 64 + fc * 16 + lr;
                    outF[(size_t)m * 1024 + n] = acc[fr][fc][r];
                }
    }
}

// ---------------- causal flash attention ----------------
// grid (S/64, B*H), block 256 (4 waves, 16 q-rows per wave)
__launch_bounds__(256)
__global__ void k_attn(const short* __restrict__ Qb, const short* __restrict__ Kb,
                       const short* __restrict__ Vtb, short* __restrict__ Ob) {
    __shared__ short p_lds[4][16][40];   // per-wave P tile, 80B rows
    int t = threadIdx.x;
    int l = t & 63, w = t >> 6;
    int lr = l & 15, lg = l >> 4;
    int bh = blockIdx.y;
    int q0 = blockIdx.x * 64;
    int qw = q0 + w * 16;

    const short* Qp = Qb + (size_t)bh * 2048 * 64;
    const short* Kp = Kb + (size_t)bh * 2048 * 64;
    const short* Vp = Vtb + (size_t)bh * 64 * 2048;

    short8v qf0 = *(const short8v*)&Qp[(size_t)(qw + lr) * 64 + lg * 8];
    short8v qf1 = *(const short8v*)&Qp[(size_t)(qw + lr) * 64 + 32 + lg * 8];

    float4v o[4] = {};
    float mr[4] = {-3e38f, -3e38f, -3e38f, -3e38f};
    float lsum[4] = {0.f, 0.f, 0.f, 0.f};

    int nch = blockIdx.x * 2 + 2;
    for (int c = 0; c < nch; c++) {
        int kv0 = c * 32;
        float4v s0 = {0.f, 0.f, 0.f, 0.f};
        float4v s1 = {0.f, 0.f, 0.f, 0.f};
        short8v kf;
        kf = *(const short8v*)&Kp[(size_t)(kv0 + lr) * 64 + lg * 8];
        s0 = __builtin_amdgcn_mfma_f32_16x16x32_bf16(qf0, kf, s0, 0, 0, 0);
        kf = *(const short8v*)&Kp[(size_t)(kv0 + lr) * 64 + 32 + lg * 8];
        s0 = __builtin_amdgcn_mfma_f32_16x16x32_bf16(qf1, kf, s0, 0, 0, 0);
        kf = *(const short8v*)&Kp[(size_t)(kv0 + 16 + lr) * 64 + lg * 8];
        s1 = __builtin_amdgcn_mfma_f32_16x16x32_bf16(qf0, kf, s1, 0, 0, 0);
        kf = *(const short8v*)&Kp[(size_t)(kv0 + 16 + lr) * 64 + 32 + lg * 8];
        s1 = __builtin_amdgcn_mfma_f32_16x16x32_bf16(qf1, kf, s1, 0, 0, 0);

        if (kv0 + 31 > qw) {   // causal mask (element-level)
#pragma unroll
            for (int r = 0; r < 4; r++) {
                int row = qw + lg * 4 + r;
                if (kv0 + lr > row) s0[r] = -3e38f;
                if (kv0 + 16 + lr > row) s1[r] = -3e38f;
            }
        }

        float p0[4], p1[4];
#pragma unroll
        for (int r = 0; r < 4; r++) {
            float mx = fmaxf(s0[r], s1[r]);
            mx = fmaxf(mx, __shfl_xor(mx, 1));
            mx = fmaxf(mx, __shfl_xor(mx, 2));
            mx = fmaxf(mx, __shfl_xor(mx, 4));
            mx = fmaxf(mx, __shfl_xor(mx, 8));
            float mnew = fmaxf(mr[r], mx);
            float sc = __expf(mr[r] - mnew);
            mr[r] = mnew;
            float e0 = __expf(s0[r] - mnew);
            float e1 = __expf(s1[r] - mnew);
            float sm = e0 + e1;
            sm += __shfl_xor(sm, 1);
            sm += __shfl_xor(sm, 2);
            sm += __shfl_xor(sm, 4);
            sm += __shfl_xor(sm, 8);
            lsum[r] = lsum[r] * sc + sm;
            o[0][r] *= sc; o[1][r] *= sc; o[2][r] *= sc; o[3][r] *= sc;
            p0[r] = e0; p1[r] = e1;
        }

        // P (D-layout) -> LDS -> A-layout fragment
#pragma unroll
        for (int r = 0; r < 4; r++) {
            p_lds[w][lg * 4 + r][lr] = f2bf(p0[r]);
            p_lds[w][lg * 4 + r][16 + lr] = f2bf(p1[r]);
        }
        short8v pa = *(const short8v*)&p_lds[w][lr][lg * 8];

#pragma unroll
        for (int dt = 0; dt < 4; dt++) {
            short8v vf = *(const short8v*)&Vp[(size_t)(dt * 16 + lr) * 2048 + kv0 + lg * 8];
            o[dt] = __builtin_amdgcn_mfma_f32_16x16x32_bf16(pa, vf, o[dt], 0, 0, 0);
        }
    }

    float inv[4];
#pragma unroll
    for (int r = 0; r < 4; r++) inv[r] = 1.0f / lsum[r];
    int b = bh >> 4, h = bh & 15;
#pragma unroll
    for (int dt = 0; dt < 4; dt++)
#pragma unroll
        for (int r = 0; r < 4; r++) {
            int q = qw + lg * 4 + r;
            Ob[((size_t)(b * 2048 + q)) * 1024 + h * 64 + dt * 16 + lr] = f2bf(o[dt][r] * inv[r]);
        }
}

extern "C" void kernel_launch(void* const* d_in, const int* in_sizes, int n_in,
                              void* d_out, int out_size, void* d_ws, size_t ws_size,
                              hipStream_t stream) {
    const float* x  = (const float*)d_in[0];
    const float* Wq = (const float*)d_in[1];
    const float* Wk = (const float*)d_in[2];
    const float* Wv = (const float*)d_in[3];
    const float* Wo = (const float*)d_in[4];
    float* out = (float*)d_out;

    char* ws = (char*)d_ws;
    short* xb  = (short*)(ws);                 // [4096][1024] bf16       8 MB
    short* Wtb = (short*)(ws + 8388608);       // 4 x [1024 n][1024 k]    8 MB
    short* Qb  = (short*)(ws + 16777216);      // [B,H,S,Dh] (pre-scaled) 8 MB
    short* Kb  = (short*)(ws + 25165824);      // [B,H,S,Dh]              8 MB
    short* Vtb = (short*)(ws + 33554432);      // [B,H,Dh,S]              8 MB
    short* Ob  = (short*)(ws + 41943040);      // [B,S,D] bf16            8 MB

    k_cvt_x<<<4096, 256, 0, stream>>>(x, xb);
    k_transpose<<<dim3(32, 32, 4), dim3(32, 8), 0, stream>>>(Wq, Wk, Wv, Wo, Wtb);
    k_gemm<<<dim3(32, 8, 3), 256, 0, stream>>>(xb, Wtb, Qb, Kb, Vtb, nullptr, 0);
    k_attn<<<dim3(32, 32), 256, 0, stream>>>(Qb, Kb, Vtb, Ob);
    k_gemm<<<dim3(32, 8, 1), 256, 0, stream>>>(Ob, Wtb + 3 * 1048576, nullptr, nullptr, nullptr, out, 1);
}

// Round 2
// 285.729 us; speedup vs baseline: 1.1207x; 1.1207x over previous
//
#include <hip/hip_runtime.h>

typedef __attribute__((ext_vector_type(4))) short short4v;
typedef __attribute__((ext_vector_type(8))) short short8v;
typedef __attribute__((ext_vector_type(4))) float float4v;
typedef __attribute__((ext_vector_type(4))) int int4v;

__device__ __forceinline__ short f2bf(float f) {
    unsigned u = __builtin_bit_cast(unsigned, f);
    u += 0x7fffu + ((u >> 16) & 1u);
    return (short)(u >> 16);
}

// ---------------- x: fp32 -> bf16 (vectorized) ----------------
__global__ void k_cvt_x(const float* __restrict__ x, short* __restrict__ xb) {
    int i = blockIdx.x * blockDim.x + threadIdx.x;
    float4v v = ((const float4v*)x)[i];
    short4v o;
    o[0] = f2bf(v[0]); o[1] = f2bf(v[1]); o[2] = f2bf(v[2]); o[3] = f2bf(v[3]);
    ((short4v*)xb)[i] = o;
}

// ---------------- W[k][n] fp32 -> Wt[n][k] bf16 (LDS tile transpose) ----------------
__global__ void k_transpose(const float* __restrict__ W0, const float* __restrict__ W1,
                            const float* __restrict__ W2, const float* __restrict__ W3,
                            short* __restrict__ Wt) {
    const float* W = blockIdx.z == 0 ? W0 : blockIdx.z == 1 ? W1 : blockIdx.z == 2 ? W2 : W3;
    short* dst = Wt + (size_t)blockIdx.z * 1024 * 1024;
    __shared__ float tile[32][33];
    int x0 = blockIdx.x * 32, y0 = blockIdx.y * 32;
    int tx = threadIdx.x, ty = threadIdx.y;
#pragma unroll
    for (int j = 0; j < 4; j++) {
        int r = ty + j * 8;
        tile[r][tx] = W[(size_t)(y0 + r) * 1024 + x0 + tx];
    }
    __syncthreads();
#pragma unroll
    for (int j = 0; j < 4; j++) {
        int r = ty + j * 8;
        dst[(size_t)(x0 + r) * 1024 + y0 + tx] = f2bf(tile[tx][r]);
    }
}

// ---------------- bf16 MFMA GEMM: C[4096x1024] = A[4096x1024] @ Bt[n][k]^T ----------------
__launch_bounds__(256)
__global__ void k_gemm(const short* __restrict__ A, const short* __restrict__ Bt,
                       short* __restrict__ outQ, short* __restrict__ outK,
                       short* __restrict__ outVt, float* __restrict__ outF, int mode) {
    __shared__ short As[128][40];
    __shared__ short Bs[128][40];
    int t = threadIdx.x;
    int l = t & 63, w = t >> 6;
    int wr = w >> 1, wc = w & 1;
    int lr = l & 15, lg = l >> 4;
    int m0 = blockIdx.x * 128;
    int n0 = blockIdx.y * 128;
    int which = (mode == 0) ? blockIdx.z : 3;
    const short* Bp = (mode == 0) ? Bt + (size_t)which * 1048576 : Bt;

    float4v acc[4][4] = {};

    for (int k0 = 0; k0 < 1024; k0 += 32) {
#pragma unroll
        for (int i = 0; i < 2; i++) {
            int e = t + i * 256;
            int row = e >> 2, kc = (e & 3) * 8;
            *(int4v*)&As[row][kc] = *(const int4v*)&A[(size_t)(m0 + row) * 1024 + k0 + kc];
            *(int4v*)&Bs[row][kc] = *(const int4v*)&Bp[(size_t)(n0 + row) * 1024 + k0 + kc];
        }
        __syncthreads();
        short8v af[4], bfr[4];
#pragma unroll
        for (int fr = 0; fr < 4; fr++) af[fr] = *(const short8v*)&As[wr * 64 + fr * 16 + lr][lg * 8];
#pragma unroll
        for (int fc = 0; fc < 4; fc++) bfr[fc] = *(const short8v*)&Bs[wc * 64 + fc * 16 + lr][lg * 8];
#pragma unroll
        for (int fr = 0; fr < 4; fr++)
#pragma unroll
            for (int fc = 0; fc < 4; fc++)
                acc[fr][fc] = __builtin_amdgcn_mfma_f32_16x16x32_bf16(af[fr], bfr[fc], acc[fr][fc], 0, 0, 0);
        __syncthreads();
    }

    if (mode == 0) {
        short* out = which == 0 ? outQ : which == 1 ? outK : outVt;
        // Q pre-scale: 1/sqrt(64) * log2(e) so attention works in exp2 domain
        float scale = (which == 0) ? 0.125f * 1.44269504088896f : 1.0f;
#pragma unroll
        for (int fr = 0; fr < 4; fr++)
#pragma unroll
            for (int fc = 0; fc < 4; fc++)
#pragma unroll
                for (int r = 0; r < 4; r++) {
                    int m = m0 + wr * 64 + fr * 16 + lg * 4 + r;
                    int n = n0 + wc * 64 + fc * 16 + lr;
                    float v = acc[fr][fc][r] * scale;
                    int b = m >> 11, s = m & 2047, h = n >> 6, dh = n & 63;
                    if (which < 2)
                        out[(((size_t)(b * 16 + h)) * 2048 + s) * 64 + dh] = f2bf(v);
                    else
                        out[(((size_t)(b * 16 + h)) * 64 + dh) * 2048 + s] = f2bf(v);
                }
    } else {
#pragma unroll
        for (int fr = 0; fr < 4; fr++)
#pragma unroll
            for (int fc = 0; fc < 4; fc++)
#pragma unroll
                for (int r = 0; r < 4; r++) {
                    int m = m0 + wr * 64 + fr * 16 + lg * 4 + r;
                    int n = n0 + wc * 64 + fc * 16 + lr;
                    outF[(size_t)m * 1024 + n] = acc[fr][fc][r];
                }
    }
}

// ---------------- causal flash attention v2 ----------------
// grid (64, B*H), block 128 = 2 waves; each wave owns a 16-row q-tile, KVBLK=64,
// register-double-buffered K, V loads issued before softmax, exp2-domain softmax.
__launch_bounds__(128)
__global__ void k_attn(const short* __restrict__ Qb, const short* __restrict__ Kb,
                       const short* __restrict__ Vtb, short* __restrict__ Ob) {
    __shared__ short p_lds[2][16][72];   // per-wave P tile [q16][kv64+pad]
    int t = threadIdx.x;
    int l = t & 63, w = t >> 6;
    int lr = l & 15, lg = l >> 4;
    int bh = blockIdx.y;
    int qt = blockIdx.x * 2 + w;         // q-tile index 0..127
    int q0 = qt * 16;

    const short* Qp = Qb + (size_t)bh * 2048 * 64;
    const short* Kp = Kb + (size_t)bh * 2048 * 64;
    const short* Vp = Vtb + (size_t)bh * 64 * 2048;

    short8v qf0 = *(const short8v*)&Qp[(size_t)(q0 + lr) * 64 + lg * 8];
    short8v qf1 = *(const short8v*)&Qp[(size_t)(q0 + lr) * 64 + 32 + lg * 8];

    float4v o[4] = {};
    float mr[4] = {-3e38f, -3e38f, -3e38f, -3e38f};
    float lsum[4] = {0.f, 0.f, 0.f, 0.f};

    int nch = (qt >> 2) + 1;             // 64-kv chunks to cover rows q0..q0+15

    short8v kf[8], kn[8];
#pragma unroll
    for (int t4 = 0; t4 < 4; t4++) {
        kf[2 * t4]     = *(const short8v*)&Kp[(size_t)(t4 * 16 + lr) * 64 + lg * 8];
        kf[2 * t4 + 1] = *(const short8v*)&Kp[(size_t)(t4 * 16 + lr) * 64 + 32 + lg * 8];
    }

    for (int c = 0; c < nch; c++) {
        int kv0 = c * 64;
        int kb = (c + 1 < nch) ? kv0 + 64 : kv0;   // clamped prefetch address
#pragma unroll
        for (int t4 = 0; t4 < 4; t4++) {
            kn[2 * t4]     = *(const short8v*)&Kp[(size_t)(kb + t4 * 16 + lr) * 64 + lg * 8];
            kn[2 * t4 + 1] = *(const short8v*)&Kp[(size_t)(kb + t4 * 16 + lr) * 64 + 32 + lg * 8];
        }

        float4v s[4] = {};
        __builtin_amdgcn_s_setprio(1);
#pragma unroll
        for (int t4 = 0; t4 < 4; t4++) {
            s[t4] = __builtin_amdgcn_mfma_f32_16x16x32_bf16(qf0, kf[2 * t4], s[t4], 0, 0, 0);
            s[t4] = __builtin_amdgcn_mfma_f32_16x16x32_bf16(qf1, kf[2 * t4 + 1], s[t4], 0, 0, 0);
        }
        __builtin_amdgcn_s_setprio(0);

        // V loads issued now; latency hides under softmax VALU chain
        short8v vf[8];
#pragma unroll
        for (int dt = 0; dt < 4; dt++) {
            vf[dt]     = *(const short8v*)&Vp[(size_t)(dt * 16 + lr) * 2048 + kv0 + lg * 8];
            vf[4 + dt] = *(const short8v*)&Vp[(size_t)(dt * 16 + lr) * 2048 + kv0 + 32 + lg * 8];
        }

        if (c == nch - 1) {   // only the last chunk crosses the causal boundary
#pragma unroll
            for (int t4 = 0; t4 < 4; t4++)
#pragma unroll
                for (int r = 0; r < 4; r++) {
                    int row = q0 + lg * 4 + r;
                    if (kv0 + t4 * 16 + lr > row) s[t4][r] = -3e38f;
                }
        }

#pragma unroll
        for (int r = 0; r < 4; r++) {
            float mx = fmaxf(fmaxf(s[0][r], s[1][r]), fmaxf(s[2][r], s[3][r]));
            mx = fmaxf(mx, __shfl_xor(mx, 1));
            mx = fmaxf(mx, __shfl_xor(mx, 2));
            mx = fmaxf(mx, __shfl_xor(mx, 4));
            mx = fmaxf(mx, __shfl_xor(mx, 8));
            float mnew = fmaxf(mr[r], mx);
            float sc = __builtin_amdgcn_exp2f(mr[r] - mnew);
            mr[r] = mnew;
            float e0 = __builtin_amdgcn_exp2f(s[0][r] - mnew);
            float e1 = __builtin_amdgcn_exp2f(s[1][r] - mnew);
            float e2 = __builtin_amdgcn_exp2f(s[2][r] - mnew);
            float e3 = __builtin_amdgcn_exp2f(s[3][r] - mnew);
            float sm = (e0 + e1) + (e2 + e3);
            sm += __shfl_xor(sm, 1);
            sm += __shfl_xor(sm, 2);
            sm += __shfl_xor(sm, 4);
            sm += __shfl_xor(sm, 8);
            lsum[r] = lsum[r] * sc + sm;
            o[0][r] *= sc; o[1][r] *= sc; o[2][r] *= sc; o[3][r] *= sc;
            p_lds[w][lg * 4 + r][lr]      = f2bf(e0);
            p_lds[w][lg * 4 + r][16 + lr] = f2bf(e1);
            p_lds[w][lg * 4 + r][32 + lr] = f2bf(e2);
            p_lds[w][lg * 4 + r][48 + lr] = f2bf(e3);
        }

        short8v pa0 = *(const short8v*)&p_lds[w][lr][lg * 8];
        short8v pa1 = *(const short8v*)&p_lds[w][lr][32 + lg * 8];

        __builtin_amdgcn_s_setprio(1);
#pragma unroll
        for (int dt = 0; dt < 4; dt++) {
            o[dt] = __builtin_amdgcn_mfma_f32_16x16x32_bf16(pa0, vf[dt], o[dt], 0, 0, 0);
            o[dt] = __builtin_amdgcn_mfma_f32_16x16x32_bf16(pa1, vf[4 + dt], o[dt], 0, 0, 0);
        }
        __builtin_amdgcn_s_setprio(0);

#pragma unroll
        for (int i = 0; i < 8; i++) kf[i] = kn[i];
    }

    float inv[4];
#pragma unroll
    for (int r = 0; r < 4; r++) inv[r] = 1.0f / lsum[r];
    int b = bh >> 4, h = bh & 15;
#pragma unroll
    for (int dt = 0; dt < 4; dt++)
#pragma unroll
        for (int r = 0; r < 4; r++) {
            int q = q0 + lg * 4 + r;
            Ob[((size_t)(b * 2048 + q)) * 1024 + h * 64 + dt * 16 + lr] = f2bf(o[dt][r] * inv[r]);
        }
}

extern "C" void kernel_launch(void* const* d_in, const int* in_sizes, int n_in,
                              void* d_out, int out_size, void* d_ws, size_t ws_size,
                              hipStream_t stream) {
    const float* x  = (const float*)d_in[0];
    const float* Wq = (const float*)d_in[1];
    const float* Wk = (const float*)d_in[2];
    const float* Wv = (const float*)d_in[3];
    const float* Wo = (const float*)d_in[4];
    float* out = (float*)d_out;

    char* ws = (char*)d_ws;
    short* xb  = (short*)(ws);                 // [4096][1024] bf16       8 MB
    short* Wtb = (short*)(ws + 8388608);       // 4 x [1024 n][1024 k]    8 MB
    short* Qb  = (short*)(ws + 16777216);      // [B,H,S,Dh] (pre-scaled) 8 MB
    short* Kb  = (short*)(ws + 25165824);      // [B,H,S,Dh]              8 MB
    short* Vtb = (short*)(ws + 33554432);      // [B,H,Dh,S]              8 MB
    short* Ob  = (short*)(ws + 41943040);      // [B,S,D] bf16            8 MB

    k_cvt_x<<<4096, 256, 0, stream>>>(x, xb);
    k_transpose<<<dim3(32, 32, 4), dim3(32, 8), 0, stream>>>(Wq, Wk, Wv, Wo, Wtb);
    k_gemm<<<dim3(32, 8, 3), 256, 0, stream>>>(xb, Wtb, Qb, Kb, Vtb, nullptr, 0);
    k_attn<<<dim3(64, 32), 128, 0, stream>>>(Qb, Kb, Vtb, Ob);
    k_gemm<<<dim3(32, 8, 1), 256, 0, stream>>>(Ob, Wtb + 3 * 1048576, nullptr, nullptr, nullptr, out, 1);
}

// Round 3
// 160.279 us; speedup vs baseline: 1.9979x; 1.7827x over previous
//
#include <hip/hip_runtime.h>

typedef __attribute__((ext_vector_type(4))) short short4v;
typedef __attribute__((ext_vector_type(8))) short short8v;
typedef __attribute__((ext_vector_type(4))) float float4v;
typedef __attribute__((ext_vector_type(4))) int int4v;

#define GLD_LDS16(gsrc, ldst)                                                             \
    __builtin_amdgcn_global_load_lds(                                                     \
        (const __attribute__((address_space(1))) void*)(gsrc),                            \
        (__attribute__((address_space(3))) void*)(ldst), 16, 0, 0)

__device__ __forceinline__ short f2bf(float f) {
    unsigned u = __builtin_bit_cast(unsigned, f);
    u += 0x7fffu + ((u >> 16) & 1u);
    return (short)(u >> 16);
}

// ---------------- x: fp32 -> bf16 (vectorized) ----------------
__global__ void k_cvt_x(const float* __restrict__ x, short* __restrict__ xb) {
    int i = blockIdx.x * blockDim.x + threadIdx.x;
    float4v v = ((const float4v*)x)[i];
    short4v o;
    o[0] = f2bf(v[0]); o[1] = f2bf(v[1]); o[2] = f2bf(v[2]); o[3] = f2bf(v[3]);
    ((short4v*)xb)[i] = o;
}

// ---------------- W[k][n] fp32 -> Wt[n][k] bf16 (LDS tile transpose) ----------------
__global__ void k_transpose(const float* __restrict__ W0, const float* __restrict__ W1,
                            const float* __restrict__ W2, const float* __restrict__ W3,
                            short* __restrict__ Wt) {
    const float* W = blockIdx.z == 0 ? W0 : blockIdx.z == 1 ? W1 : blockIdx.z == 2 ? W2 : W3;
    short* dst = Wt + (size_t)blockIdx.z * 1024 * 1024;
    __shared__ float tile[32][33];
    int x0 = blockIdx.x * 32, y0 = blockIdx.y * 32;
    int tx = threadIdx.x, ty = threadIdx.y;
#pragma unroll
    for (int j = 0; j < 4; j++) {
        int r = ty + j * 8;
        tile[r][tx] = W[(size_t)(y0 + r) * 1024 + x0 + tx];
    }
    __syncthreads();
#pragma unroll
    for (int j = 0; j < 4; j++) {
        int r = ty + j * 8;
        dst[(size_t)(x0 + r) * 1024 + y0 + tx] = f2bf(tile[tx][r]);
    }
}

// ---------------- bf16 MFMA GEMM (m97 structure: global_load_lds w16, linear LDS) ----
__launch_bounds__(256)
__global__ void k_gemm(const short* __restrict__ A, const short* __restrict__ Bt,
                       short* __restrict__ outQ, short* __restrict__ outK,
                       short* __restrict__ outVt, float* __restrict__ outF, int mode) {
    __shared__ short As[128][32];
    __shared__ short Bs[128][32];
    int t = threadIdx.x;
    int l = t & 63, w = t >> 6;
    int wr = w >> 1, wc = w & 1;
    int lr = l & 15, lg = l >> 4;
    int m0 = blockIdx.x * 128;
    int n0 = blockIdx.y * 128;
    int which = (mode == 0) ? blockIdx.z : 3;
    const short* Bp = (mode == 0) ? Bt + (size_t)which * 1048576 : Bt;

    // staging: wave w stages rows [w*32, w*32+32); lane l covers row +(l>>2), col (l&3)*8
    int srow = w * 32 + (l >> 2);
    int scol = (l & 3) * 8;

    float4v acc[4][4] = {};

    for (int k0 = 0; k0 < 1024; k0 += 32) {
        GLD_LDS16(&A[(size_t)(m0 + srow) * 1024 + k0 + scol], &As[w * 32][0]);
        GLD_LDS16(&A[(size_t)(m0 + srow + 16) * 1024 + k0 + scol], &As[w * 32 + 16][0]);
        GLD_LDS16(&Bp[(size_t)(n0 + srow) * 1024 + k0 + scol], &Bs[w * 32][0]);
        GLD_LDS16(&Bp[(size_t)(n0 + srow + 16) * 1024 + k0 + scol], &Bs[w * 32 + 16][0]);
        __syncthreads();
        short8v af[4], bfr[4];
#pragma unroll
        for (int fr = 0; fr < 4; fr++) af[fr] = *(const short8v*)&As[wr * 64 + fr * 16 + lr][lg * 8];
#pragma unroll
        for (int fc = 0; fc < 4; fc++) bfr[fc] = *(const short8v*)&Bs[wc * 64 + fc * 16 + lr][lg * 8];
#pragma unroll
        for (int fr = 0; fr < 4; fr++)
#pragma unroll
            for (int fc = 0; fc < 4; fc++)
                acc[fr][fc] = __builtin_amdgcn_mfma_f32_16x16x32_bf16(af[fr], bfr[fc], acc[fr][fc], 0, 0, 0);
        __syncthreads();
    }

    if (mode == 0) {
        short* out = which == 0 ? outQ : which == 1 ? outK : outVt;
        // Q pre-scale: 1/sqrt(64) * log2(e) so attention works in exp2 domain
        float scale = (which == 0) ? 0.125f * 1.44269504088896f : 1.0f;
#pragma unroll
        for (int fr = 0; fr < 4; fr++)
#pragma unroll
            for (int fc = 0; fc < 4; fc++)
#pragma unroll
                for (int r = 0; r < 4; r++) {
                    int m = m0 + wr * 64 + fr * 16 + lg * 4 + r;
                    int n = n0 + wc * 64 + fc * 16 + lr;
                    float v = acc[fr][fc][r] * scale;
                    int b = m >> 11, s = m & 2047, h = n >> 6, dh = n & 63;
                    if (which < 2)
                        out[(((size_t)(b * 16 + h)) * 2048 + s) * 64 + dh] = f2bf(v);
                    else
                        out[(((size_t)(b * 16 + h)) * 64 + dh) * 2048 + s] = f2bf(v);
                }
    } else {
#pragma unroll
        for (int fr = 0; fr < 4; fr++)
#pragma unroll
            for (int fc = 0; fc < 4; fc++)
#pragma unroll
                for (int r = 0; r < 4; r++) {
                    int m = m0 + wr * 64 + fr * 16 + lg * 4 + r;
                    int n = n0 + wc * 64 + fc * 16 + lr;
                    outF[(size_t)m * 1024 + n] = acc[fr][fc][r];
                }
    }
}

// ---------------- causal flash attention v3 ----------------
// grid (16, B*H), block 256 (4 waves). Block processes q-tile pair (31-p, p):
// 33 kv-chunks of 64 -> perfectly balanced. K/V^T chunks double-buffered in padded
// LDS (reg-staged, T14 issue-early/write-late). Each wave owns 16 q-rows per tile.
__launch_bounds__(256, 2)
__global__ void k_attn(const short* __restrict__ Qb, const short* __restrict__ Kb,
                       const short* __restrict__ Vtb, short* __restrict__ Ob) {
    __shared__ short K_lds[2][64][72];
    __shared__ short V_lds[2][64][72];
    __shared__ short p_lds[4][16][72];
    int t = threadIdx.x;
    int l = t & 63, w = t >> 6;
    int lr = l & 15, lg = l >> 4;
    int bh = blockIdx.y;
    int p = blockIdx.x;                 // pair index 0..15

    const short* Qp = Qb + (size_t)bh * 2048 * 64;
    const short* Kp = Kb + (size_t)bh * 2048 * 64;
    const short* Vp = Vtb + (size_t)bh * 64 * 2048;

    int n0 = 32 - p;                    // chunks for tile hi = 31-p
    int n1 = p + 1;                     // chunks for tile lo = p
    const int total = 33;

    // staging map: thread t covers 16B slots t and t+256 of each 8KB chunk
    int srow = t >> 3;                  // 0..31
    int scol = (t & 7) * 8;

    // prologue: chunk 0 -> regs -> buf 0
    int4v rk0 = *(const int4v*)&Kp[(size_t)srow * 64 + scol];
    int4v rk1 = *(const int4v*)&Kp[(size_t)(srow + 32) * 64 + scol];
    int4v rv0 = *(const int4v*)&Vp[(size_t)srow * 2048 + scol];
    int4v rv1 = *(const int4v*)&Vp[(size_t)(srow + 32) * 2048 + scol];
    *(int4v*)&K_lds[0][srow][scol] = rk0;
    *(int4v*)&K_lds[0][srow + 32][scol] = rk1;
    *(int4v*)&V_lds[0][srow][scol] = rv0;
    *(int4v*)&V_lds[0][srow + 32][scol] = rv1;
    __syncthreads();

    int tile = 31 - p;
    int q0 = tile * 64 + w * 16;
    short8v qf0 = *(const short8v*)&Qp[(size_t)(q0 + lr) * 64 + lg * 8];
    short8v qf1 = *(const short8v*)&Qp[(size_t)(q0 + lr) * 64 + 32 + lg * 8];

    float4v o[4] = {};
    float mr[4] = {-3e38f, -3e38f, -3e38f, -3e38f};
    float lsum[4] = {0.f, 0.f, 0.f, 0.f};
    int cur = 0;
    int b = bh >> 4, h = bh & 15;

    for (int ci = 0; ci < total; ci++) {
        bool second = ci >= n0;
        int ntile = second ? n1 : n0;
        int c = second ? ci - n0 : ci;
        int kv0 = c * 64;

        // issue next-chunk global loads early (latency hides under compute)
        int cin = ci + 1;
        int kvn = (cin < total) ? ((cin < n0) ? cin * 64 : (cin - n0) * 64) : 0;
        rk0 = *(const int4v*)&Kp[(size_t)(kvn + srow) * 64 + scol];
        rk1 = *(const int4v*)&Kp[(size_t)(kvn + srow + 32) * 64 + scol];
        rv0 = *(const int4v*)&Vp[(size_t)srow * 2048 + kvn + scol];
        rv1 = *(const int4v*)&Vp[(size_t)(srow + 32) * 2048 + kvn + scol];

        // ---- QK^T from LDS ----
        float4v s[4] = {};
        __builtin_amdgcn_s_setprio(1);
#pragma unroll
        for (int t4 = 0; t4 < 4; t4++) {
            short8v kfa = *(const short8v*)&K_lds[cur][t4 * 16 + lr][lg * 8];
            short8v kfb = *(const short8v*)&K_lds[cur][t4 * 16 + lr][32 + lg * 8];
            s[t4] = __builtin_amdgcn_mfma_f32_16x16x32_bf16(qf0, kfa, s[t4], 0, 0, 0);
            s[t4] = __builtin_amdgcn_mfma_f32_16x16x32_bf16(qf1, kfb, s[t4], 0, 0, 0);
        }
        __builtin_amdgcn_s_setprio(0);

        if (c == ntile - 1) {           // causal boundary chunk
#pragma unroll
            for (int t4 = 0; t4 < 4; t4++)
#pragma unroll
                for (int r = 0; r < 4; r++) {
                    int row = q0 + lg * 4 + r;
                    if (kv0 + t4 * 16 + lr > row) s[t4][r] = -3e38f;
                }
        }

        // ---- online softmax (exp2 domain; Q pre-scaled by 1/8*log2e) ----
#pragma unroll
        for (int r = 0; r < 4; r++) {
            float mx = fmaxf(fmaxf(s[0][r], s[1][r]), fmaxf(s[2][r], s[3][r]));
            mx = fmaxf(mx, __shfl_xor(mx, 1));
            mx = fmaxf(mx, __shfl_xor(mx, 2));
            mx = fmaxf(mx, __shfl_xor(mx, 4));
            mx = fmaxf(mx, __shfl_xor(mx, 8));
            float mnew = fmaxf(mr[r], mx);
            float sc = __builtin_amdgcn_exp2f(mr[r] - mnew);
            mr[r] = mnew;
            float e0 = __builtin_amdgcn_exp2f(s[0][r] - mnew);
            float e1 = __builtin_amdgcn_exp2f(s[1][r] - mnew);
            float e2 = __builtin_amdgcn_exp2f(s[2][r] - mnew);
            float e3 = __builtin_amdgcn_exp2f(s[3][r] - mnew);
            float sm = (e0 + e1) + (e2 + e3);
            sm += __shfl_xor(sm, 1);
            sm += __shfl_xor(sm, 2);
            sm += __shfl_xor(sm, 4);
            sm += __shfl_xor(sm, 8);
            lsum[r] = lsum[r] * sc + sm;
            o[0][r] *= sc; o[1][r] *= sc; o[2][r] *= sc; o[3][r] *= sc;
            p_lds[w][lg * 4 + r][lr]      = f2bf(e0);
            p_lds[w][lg * 4 + r][16 + lr] = f2bf(e1);
            p_lds[w][lg * 4 + r][32 + lr] = f2bf(e2);
            p_lds[w][lg * 4 + r][48 + lr] = f2bf(e3);
        }

        short8v pa0 = *(const short8v*)&p_lds[w][lr][lg * 8];
        short8v pa1 = *(const short8v*)&p_lds[w][lr][32 + lg * 8];

        // ---- PV from LDS V^T ----
        __builtin_amdgcn_s_setprio(1);
#pragma unroll
        for (int dt = 0; dt < 4; dt++) {
            short8v vfa = *(const short8v*)&V_lds[cur][dt * 16 + lr][lg * 8];
            short8v vfb = *(const short8v*)&V_lds[cur][dt * 16 + lr][32 + lg * 8];
            o[dt] = __builtin_amdgcn_mfma_f32_16x16x32_bf16(pa0, vfa, o[dt], 0, 0, 0);
            o[dt] = __builtin_amdgcn_mfma_f32_16x16x32_bf16(pa1, vfb, o[dt], 0, 0, 0);
        }
        __builtin_amdgcn_s_setprio(0);

        // ---- tile finalize / switch ----
        if (c == ntile - 1) {
            float inv[4];
#pragma unroll
            for (int r = 0; r < 4; r++) inv[r] = 1.0f / lsum[r];
#pragma unroll
            for (int dt = 0; dt < 4; dt++)
#pragma unroll
                for (int r = 0; r < 4; r++) {
                    int q = q0 + lg * 4 + r;
                    Ob[((size_t)(b * 2048 + q)) * 1024 + h * 64 + dt * 16 + lr] = f2bf(o[dt][r] * inv[r]);
                }
            if (!second) {
                tile = p;
                q0 = tile * 64 + w * 16;
                qf0 = *(const short8v*)&Qp[(size_t)(q0 + lr) * 64 + lg * 8];
                qf1 = *(const short8v*)&Qp[(size_t)(q0 + lr) * 64 + 32 + lg * 8];
#pragma unroll
                for (int dt = 0; dt < 4; dt++) o[dt] = float4v{0.f, 0.f, 0.f, 0.f};
#pragma unroll
                for (int r = 0; r < 4; r++) { mr[r] = -3e38f; lsum[r] = 0.f; }
            }
        }

        __syncthreads();                // all waves done reading buf[cur^1] (prev iter)
        *(int4v*)&K_lds[cur ^ 1][srow][scol] = rk0;
        *(int4v*)&K_lds[cur ^ 1][srow + 32][scol] = rk1;
        *(int4v*)&V_lds[cur ^ 1][srow][scol] = rv0;
        *(int4v*)&V_lds[cur ^ 1][srow + 32][scol] = rv1;
        __syncthreads();                // staged chunk visible
        cur ^= 1;
    }
}

extern "C" void kernel_launch(void* const* d_in, const int* in_sizes, int n_in,
                              void* d_out, int out_size, void* d_ws, size_t ws_size,
                              hipStream_t stream) {
    const float* x  = (const float*)d_in[0];
    const float* Wq = (const float*)d_in[1];
    const float* Wk = (const float*)d_in[2];
    const float* Wv = (const float*)d_in[3];
    const float* Wo = (const float*)d_in[4];
    float* out = (float*)d_out;

    char* ws = (char*)d_ws;
    short* xb  = (short*)(ws);                 // [4096][1024] bf16       8 MB
    short* Wtb = (short*)(ws + 8388608);       // 4 x [1024 n][1024 k]    8 MB
    short* Qb  = (short*)(ws + 16777216);      // [B,H,S,Dh] (pre-scaled) 8 MB
    short* Kb  = (short*)(ws + 25165824);      // [B,H,S,Dh]              8 MB
    short* Vtb = (short*)(ws + 33554432);      // [B,H,Dh,S]              8 MB
    short* Ob  = (short*)(ws + 41943040);      // [B,S,D] bf16            8 MB

    k_cvt_x<<<4096, 256, 0, stream>>>(x, xb);
    k_transpose<<<dim3(32, 32, 4), dim3(32, 8), 0, stream>>>(Wq, Wk, Wv, Wo, Wtb);
    k_gemm<<<dim3(32, 8, 3), 256, 0, stream>>>(xb, Wtb, Qb, Kb, Vtb, nullptr, 0);
    k_attn<<<dim3(16, 32), 256, 0, stream>>>(Qb, Kb, Vtb, Ob);
    k_gemm<<<dim3(32, 8, 1), 256, 0, stream>>>(Ob, Wtb + 3 * 1048576, nullptr, nullptr, nullptr, out, 1);
}

// Round 4
// 150.397 us; speedup vs baseline: 2.1292x; 1.0657x over previous
//
#include <hip/hip_runtime.h>

typedef __attribute__((ext_vector_type(4))) short short4v;
typedef __attribute__((ext_vector_type(8))) short short8v;
typedef __attribute__((ext_vector_type(4))) float float4v;
typedef __attribute__((ext_vector_type(4))) int int4v;

#define GLD_LDS16(gsrc, ldst)                                                             \
    __builtin_amdgcn_global_load_lds(                                                     \
        (const __attribute__((address_space(1))) void*)(gsrc),                            \
        (__attribute__((address_space(3))) void*)(ldst), 16, 0, 0)

__device__ __forceinline__ short f2bf(float f) {
    unsigned u = __builtin_bit_cast(unsigned, f);
    u += 0x7fffu + ((u >> 16) & 1u);
    return (short)(u >> 16);
}

// ---------------- x: fp32 -> bf16 (vectorized) ----------------
__global__ void k_cvt_x(const float* __restrict__ x, short* __restrict__ xb) {
    int i = blockIdx.x * blockDim.x + threadIdx.x;
    float4v v = ((const float4v*)x)[i];
    short4v o;
    o[0] = f2bf(v[0]); o[1] = f2bf(v[1]); o[2] = f2bf(v[2]); o[3] = f2bf(v[3]);
    ((short4v*)xb)[i] = o;
}

// ---------------- W[k][n] fp32 -> Wt[n][k] bf16 (LDS tile transpose) ----------------
__global__ void k_transpose(const float* __restrict__ W0, const float* __restrict__ W1,
                            const float* __restrict__ W2, const float* __restrict__ W3,
                            short* __restrict__ Wt) {
    const float* W = blockIdx.z == 0 ? W0 : blockIdx.z == 1 ? W1 : blockIdx.z == 2 ? W2 : W3;
    short* dst = Wt + (size_t)blockIdx.z * 1024 * 1024;
    __shared__ float tile[32][33];
    int x0 = blockIdx.x * 32, y0 = blockIdx.y * 32;
    int tx = threadIdx.x, ty = threadIdx.y;
#pragma unroll
    for (int j = 0; j < 4; j++) {
        int r = ty + j * 8;
        tile[r][tx] = W[(size_t)(y0 + r) * 1024 + x0 + tx];
    }
    __syncthreads();
#pragma unroll
    for (int j = 0; j < 4; j++) {
        int r = ty + j * 8;
        dst[(size_t)(x0 + r) * 1024 + y0 + tx] = f2bf(tile[tx][r]);
    }
}

// ---------------- bf16 MFMA GEMM (m97 structure: global_load_lds w16, linear LDS) ----
__launch_bounds__(256)
__global__ void k_gemm(const short* __restrict__ A, const short* __restrict__ Bt,
                       short* __restrict__ outQ, short* __restrict__ outK,
                       short* __restrict__ outVt, float* __restrict__ outF, int mode) {
    __shared__ short As[128][32];
    __shared__ short Bs[128][32];
    int t = threadIdx.x;
    int l = t & 63, w = t >> 6;
    int wr = w >> 1, wc = w & 1;
    int lr = l & 15, lg = l >> 4;
    int m0 = blockIdx.x * 128;
    int n0 = blockIdx.y * 128;
    int which = (mode == 0) ? blockIdx.z : 3;
    const short* Bp = (mode == 0) ? Bt + (size_t)which * 1048576 : Bt;

    int srow = w * 32 + (l >> 2);
    int scol = (l & 3) * 8;

    float4v acc[4][4] = {};

    for (int k0 = 0; k0 < 1024; k0 += 32) {
        GLD_LDS16(&A[(size_t)(m0 + srow) * 1024 + k0 + scol], &As[w * 32][0]);
        GLD_LDS16(&A[(size_t)(m0 + srow + 16) * 1024 + k0 + scol], &As[w * 32 + 16][0]);
        GLD_LDS16(&Bp[(size_t)(n0 + srow) * 1024 + k0 + scol], &Bs[w * 32][0]);
        GLD_LDS16(&Bp[(size_t)(n0 + srow + 16) * 1024 + k0 + scol], &Bs[w * 32 + 16][0]);
        __syncthreads();
        short8v af[4], bfr[4];
#pragma unroll
        for (int fr = 0; fr < 4; fr++) af[fr] = *(const short8v*)&As[wr * 64 + fr * 16 + lr][lg * 8];
#pragma unroll
        for (int fc = 0; fc < 4; fc++) bfr[fc] = *(const short8v*)&Bs[wc * 64 + fc * 16 + lr][lg * 8];
#pragma unroll
        for (int fr = 0; fr < 4; fr++)
#pragma unroll
            for (int fc = 0; fc < 4; fc++)
                acc[fr][fc] = __builtin_amdgcn_mfma_f32_16x16x32_bf16(af[fr], bfr[fc], acc[fr][fc], 0, 0, 0);
        __syncthreads();
    }

    if (mode == 0) {
        short* out = which == 0 ? outQ : which == 1 ? outK : outVt;
        float scale = (which == 0) ? 0.125f * 1.44269504088896f : 1.0f;
#pragma unroll
        for (int fr = 0; fr < 4; fr++)
#pragma unroll
            for (int fc = 0; fc < 4; fc++)
#pragma unroll
                for (int r = 0; r < 4; r++) {
                    int m = m0 + wr * 64 + fr * 16 + lg * 4 + r;
                    int n = n0 + wc * 64 + fc * 16 + lr;
                    float v = acc[fr][fc][r] * scale;
                    int b = m >> 11, s = m & 2047, h = n >> 6, dh = n & 63;
                    if (which < 2)
                        out[(((size_t)(b * 16 + h)) * 2048 + s) * 64 + dh] = f2bf(v);
                    else
                        out[(((size_t)(b * 16 + h)) * 64 + dh) * 2048 + s] = f2bf(v);
                }
    } else {
#pragma unroll
        for (int fr = 0; fr < 4; fr++)
#pragma unroll
            for (int fc = 0; fc < 4; fc++)
#pragma unroll
                for (int r = 0; r < 4; r++) {
                    int m = m0 + wr * 64 + fr * 16 + lg * 4 + r;
                    int n = n0 + wc * 64 + fc * 16 + lr;
                    outF[(size_t)m * 1024 + n] = acc[fr][fc][r];
                }
    }
}

// ---------------- causal flash attention v4 ----------------
// grid (16, B*H) remapped XCD-aware. Block = 4 waves, q-tile pair (31-p, p) = 33 chunks.
// K/V^T double-buffered in linear LDS via async global_load_lds (w16), XOR-swizzled
// source + XOR-swizzled ds_read (involution both sides). One barrier per chunk.
__launch_bounds__(256, 2)
__global__ void k_attn(const short* __restrict__ Qb, const short* __restrict__ Kb,
                       const short* __restrict__ Vtb, short* __restrict__ Ob) {
    __shared__ short K_lds[2][64][64];
    __shared__ short V_lds[2][64][64];
    __shared__ short p_lds[4][16][72];
    int t = threadIdx.x;
    int l = t & 63, w = t >> 6;
    int lr = l & 15, lg = l >> 4;

    // XCD-aware remap: all 16 blocks of one (b,h) share linear%8 -> same XCD L2
    int L = blockIdx.y * 16 + blockIdx.x;
    int bh = (L & 7) * 4 + ((L >> 3) & 3);
    int p = L >> 5;

    const short* Qp = Qb + (size_t)bh * 2048 * 64;
    const short* Kp = Kb + (size_t)bh * 2048 * 64;
    const short* Vp = Vtb + (size_t)bh * 64 * 2048;

    int n0 = 32 - p;
    int n1 = p + 1;
    const int total = 33;

    // async stage one 64-kv chunk (K rows + V^T rows) into buffer bb, source-swizzled
    auto stage = [&](int bb, int kv0) {
#pragma unroll
        for (int i = 0; i < 2; i++) {
            int s = w * 64 + i * 256 + l;
            int row = s >> 3, cg = s & 7;
            int cs = (cg ^ (row & 7)) * 8;
            GLD_LDS16(&Kp[(size_t)(kv0 + row) * 64 + cs],
                      (short*)K_lds[bb] + (size_t)(w * 64 + i * 256) * 8);
            GLD_LDS16(&Vp[(size_t)row * 2048 + kv0 + cs],
                      (short*)V_lds[bb] + (size_t)(w * 64 + i * 256) * 8);
        }
    };

    stage(0, 0);

    int tile = 31 - p;
    int q0 = tile * 64 + w * 16;
    short8v qf0 = *(const short8v*)&Qp[(size_t)(q0 + lr) * 64 + lg * 8];
    short8v qf1 = *(const short8v*)&Qp[(size_t)(q0 + lr) * 64 + 32 + lg * 8];

    float4v o[4] = {};
    float mr[4] = {-3e38f, -3e38f, -3e38f, -3e38f};
    float lsum[4] = {0.f, 0.f, 0.f, 0.f};
    int cur = 0;
    int b = bh >> 4, h = bh & 15;

    __syncthreads();   // drains prologue loads (vmcnt(0) before barrier)

    for (int ci = 0; ci < total; ci++) {
        bool second = ci >= n0;
        int ntile = second ? n1 : n0;
        int c = second ? ci - n0 : ci;
        int kv0 = c * 64;

        int cin = ci + 1;
        if (cin < total) {
            int kvn = (cin < n0) ? cin * 64 : (cin - n0) * 64;
            stage(cur ^ 1, kvn);
        }

        // ---- QK^T from swizzled LDS ----
        const short* Kf = (const short*)K_lds[cur];
        float4v s[4] = {};
        __builtin_amdgcn_s_setprio(1);
#pragma unroll
        for (int t4 = 0; t4 < 4; t4++) {
            int krow = t4 * 16 + lr;
            int sw = (krow & 7);
            short8v kfa = *(const short8v*)&Kf[krow * 64 + ((lg ^ sw) * 8)];
            short8v kfb = *(const short8v*)&Kf[krow * 64 + (((lg ^ 4) ^ sw) * 8)];
            s[t4] = __builtin_amdgcn_mfma_f32_16x16x32_bf16(qf0, kfa, s[t4], 0, 0, 0);
            s[t4] = __builtin_amdgcn_mfma_f32_16x16x32_bf16(qf1, kfb, s[t4], 0, 0, 0);
        }
        __builtin_amdgcn_s_setprio(0);

        if (c == ntile - 1) {           // causal boundary chunk
#pragma unroll
            for (int t4 = 0; t4 < 4; t4++)
#pragma unroll
                for (int r = 0; r < 4; r++) {
                    int row = q0 + lg * 4 + r;
                    if (kv0 + t4 * 16 + lr > row) s[t4][r] = -3e38f;
                }
        }

        // ---- online softmax (exp2 domain), defer-max + deferred row-sum ----
        float mx[4];
#pragma unroll
        for (int r = 0; r < 4; r++) {
            float m_ = fmaxf(fmaxf(s[0][r], s[1][r]), fmaxf(s[2][r], s[3][r]));
            m_ = fmaxf(m_, __shfl_xor(m_, 1));
            m_ = fmaxf(m_, __shfl_xor(m_, 2));
            m_ = fmaxf(m_, __shfl_xor(m_, 4));
            m_ = fmaxf(m_, __shfl_xor(m_, 8));
            mx[r] = m_;
        }
        bool ok = (mx[0] - mr[0] <= 8.f) && (mx[1] - mr[1] <= 8.f) &&
                  (mx[2] - mr[2] <= 8.f) && (mx[3] - mr[3] <= 8.f);
        if (!__all((int)ok)) {
#pragma unroll
            for (int r = 0; r < 4; r++) {
                float mnew = fmaxf(mr[r], mx[r]);
                float sc = __builtin_amdgcn_exp2f(mr[r] - mnew);
                mr[r] = mnew;
                lsum[r] *= sc;
                o[0][r] *= sc; o[1][r] *= sc; o[2][r] *= sc; o[3][r] *= sc;
            }
        }
#pragma unroll
        for (int r = 0; r < 4; r++) {
            float e0 = __builtin_amdgcn_exp2f(s[0][r] - mr[r]);
            float e1 = __builtin_amdgcn_exp2f(s[1][r] - mr[r]);
            float e2 = __builtin_amdgcn_exp2f(s[2][r] - mr[r]);
            float e3 = __builtin_amdgcn_exp2f(s[3][r] - mr[r]);
            lsum[r] += (e0 + e1) + (e2 + e3);
            p_lds[w][lg * 4 + r][lr]      = f2bf(e0);
            p_lds[w][lg * 4 + r][16 + lr] = f2bf(e1);
            p_lds[w][lg * 4 + r][32 + lr] = f2bf(e2);
            p_lds[w][lg * 4 + r][48 + lr] = f2bf(e3);
        }

        short8v pa0 = *(const short8v*)&p_lds[w][lr][lg * 8];
        short8v pa1 = *(const short8v*)&p_lds[w][lr][32 + lg * 8];

        // ---- PV from swizzled LDS V^T ----
        const short* Vf = (const short*)V_lds[cur];
        __builtin_amdgcn_s_setprio(1);
#pragma unroll
        for (int dt = 0; dt < 4; dt++) {
            int vrow = dt * 16 + lr;
            int sw = (vrow & 7);
            short8v vfa = *(const short8v*)&Vf[vrow * 64 + ((lg ^ sw) * 8)];
            short8v vfb = *(const short8v*)&Vf[vrow * 64 + (((lg ^ 4) ^ sw) * 8)];
            o[dt] = __builtin_amdgcn_mfma_f32_16x16x32_bf16(pa0, vfa, o[dt], 0, 0, 0);
            o[dt] = __builtin_amdgcn_mfma_f32_16x16x32_bf16(pa1, vfb, o[dt], 0, 0, 0);
        }
        __builtin_amdgcn_s_setprio(0);

        // ---- tile finalize / switch ----
        if (c == ntile - 1) {
            float inv[4];
#pragma unroll
            for (int r = 0; r < 4; r++) {
                float ls = lsum[r];
                ls += __shfl_xor(ls, 1);
                ls += __shfl_xor(ls, 2);
                ls += __shfl_xor(ls, 4);
                ls += __shfl_xor(ls, 8);
                inv[r] = 1.0f / ls;
            }
#pragma unroll
            for (int dt = 0; dt < 4; dt++)
#pragma unroll
                for (int r = 0; r < 4; r++) {
                    int q = q0 + lg * 4 + r;
                    Ob[((size_t)(b * 2048 + q)) * 1024 + h * 64 + dt * 16 + lr] = f2bf(o[dt][r] * inv[r]);
                }
            if (!second) {
                tile = p;
                q0 = tile * 64 + w * 16;
                qf0 = *(const short8v*)&Qp[(size_t)(q0 + lr) * 64 + lg * 8];
                qf1 = *(const short8v*)&Qp[(size_t)(q0 + lr) * 64 + 32 + lg * 8];
#pragma unroll
                for (int dt = 0; dt < 4; dt++) o[dt] = float4v{0.f, 0.f, 0.f, 0.f};
#pragma unroll
                for (int r = 0; r < 4; r++) { mr[r] = -3e38f; lsum[r] = 0.f; }
            }
        }

        __syncthreads();   // vmcnt+lgkm drain: staged chunk complete, reads of buf[cur] done
        cur ^= 1;
    }
}

extern "C" void kernel_launch(void* const* d_in, const int* in_sizes, int n_in,
                              void* d_out, int out_size, void* d_ws, size_t ws_size,
                              hipStream_t stream) {
    const float* x  = (const float*)d_in[0];
    const float* Wq = (const float*)d_in[1];
    const float* Wk = (const float*)d_in[2];
    const float* Wv = (const float*)d_in[3];
    const float* Wo = (const float*)d_in[4];
    float* out = (float*)d_out;

    char* ws = (char*)d_ws;
    short* xb  = (short*)(ws);                 // [4096][1024] bf16       8 MB
    short* Wtb = (short*)(ws + 8388608);       // 4 x [1024 n][1024 k]    8 MB
    short* Qb  = (short*)(ws + 16777216);      // [B,H,S,Dh] (pre-scaled) 8 MB
    short* Kb  = (short*)(ws + 25165824);      // [B,H,S,Dh]              8 MB
    short* Vtb = (short*)(ws + 33554432);      // [B,H,Dh,S]              8 MB
    short* Ob  = (short*)(ws + 41943040);      // [B,S,D] bf16            8 MB

    k_cvt_x<<<4096, 256, 0, stream>>>(x, xb);
    k_transpose<<<dim3(32, 32, 4), dim3(32, 8), 0, stream>>>(Wq, Wk, Wv, Wo, Wtb);
    k_gemm<<<dim3(32, 8, 3), 256, 0, stream>>>(xb, Wtb, Qb, Kb, Vtb, nullptr, 0);
    k_attn<<<dim3(16, 32), 256, 0, stream>>>(Qb, Kb, Vtb, Ob);
    k_gemm<<<dim3(32, 8, 1), 256, 0, stream>>>(Ob, Wtb + 3 * 1048576, nullptr, nullptr, nullptr, out, 1);
}

// Round 5
// 123.021 us; speedup vs baseline: 2.6030x; 1.2225x over previous
//
#include <hip/hip_runtime.h>

typedef __attribute__((ext_vector_type(4))) short short4v;
typedef __attribute__((ext_vector_type(8))) short short8v;
typedef __attribute__((ext_vector_type(4))) float float4v;
typedef __attribute__((ext_vector_type(4))) int int4v;

#define GLD_LDS16(gsrc, ldst)                                                             \
    __builtin_amdgcn_global_load_lds(                                                     \
        (const __attribute__((address_space(1))) void*)(gsrc),                            \
        (__attribute__((address_space(3))) void*)(ldst), 16, 0, 0)

__device__ __forceinline__ short f2bf(float f) {
    unsigned u = __builtin_bit_cast(unsigned, f);
    u += 0x7fffu + ((u >> 16) & 1u);
    return (short)(u >> 16);
}

// ---------------- x: fp32 -> bf16 (vectorized) ----------------
__global__ void k_cvt_x(const float* __restrict__ x, short* __restrict__ xb) {
    int i = blockIdx.x * blockDim.x + threadIdx.x;
    float4v v = ((const float4v*)x)[i];
    short4v o;
    o[0] = f2bf(v[0]); o[1] = f2bf(v[1]); o[2] = f2bf(v[2]); o[3] = f2bf(v[3]);
    ((short4v*)xb)[i] = o;
}

// ---------------- W[k][n] fp32 -> Wt[n][k] bf16 (LDS tile transpose) ----------------
__global__ void k_transpose(const float* __restrict__ W0, const float* __restrict__ W1,
                            const float* __restrict__ W2, const float* __restrict__ W3,
                            short* __restrict__ Wt) {
    const float* W = blockIdx.z == 0 ? W0 : blockIdx.z == 1 ? W1 : blockIdx.z == 2 ? W2 : W3;
    short* dst = Wt + (size_t)blockIdx.z * 1024 * 1024;
    __shared__ float tile[32][33];
    int x0 = blockIdx.x * 32, y0 = blockIdx.y * 32;
    int tx = threadIdx.x, ty = threadIdx.y;
#pragma unroll
    for (int j = 0; j < 4; j++) {
        int r = ty + j * 8;
        tile[r][tx] = W[(size_t)(y0 + r) * 1024 + x0 + tx];
    }
    __syncthreads();
#pragma unroll
    for (int j = 0; j < 4; j++) {
        int r = ty + j * 8;
        dst[(size_t)(x0 + r) * 1024 + y0 + tx] = f2bf(tile[tx][r]);
    }
}

// ---------------- bf16 MFMA GEMM v2: 128x128 tile, BK=64, 8 waves, 2-phase dbuf ------
// MODE 0: Q/K (blockIdx.z = 0 -> Q w/ exp2 scale, 1 -> K), head-major bf16 out
// MODE 1: V with swapped MFMA operands -> V^T [B,H,Dh,S] with s-contiguous writes
// MODE 2: fp32 row-major out (final O-projection)
// LDS swizzle: slot(row, g) holds global col-group g^(row&7); read with same XOR.
template <int MODE>
__launch_bounds__(512, 4)
__global__ void k_gemm2(const short* __restrict__ A, const short* __restrict__ Bt,
                        short* __restrict__ out0, short* __restrict__ out1,
                        float* __restrict__ outF) {
    __shared__ short As[2][128][64];
    __shared__ short Bs[2][128][64];
    int t = threadIdx.x;
    int l = t & 63, w = t >> 6;          // 8 waves
    int wm = w >> 2, wn = w & 3;         // 2 (M) x 4 (N); wave owns 64x32 output
    int lr = l & 15, lg = l >> 4;
    int m0 = blockIdx.x * 128, n0 = blockIdx.y * 128;
    const short* Bp = Bt + (MODE == 0 ? ((size_t)blockIdx.z << 20) : 0);

    // staging lane constants: lane l covers row (w*8 + (l>>3)) (+64), col-group (l&7)^(l>>3)
    int srow = l >> 3;
    int sg = (l & 7) ^ srow;
    const short* Ab0 = A + (size_t)(m0 + w * 8 + srow) * 1024 + sg * 8;
    const short* Ab1 = Ab0 + 64 * 1024;
    const short* Bb0 = Bp + (size_t)(n0 + w * 8 + srow) * 1024 + sg * 8;
    const short* Bb1 = Bb0 + 64 * 1024;

    float4v acc[4][2] = {};

#define STAGE(bb, k0)                                   \
    do {                                                \
        GLD_LDS16(Ab0 + (k0), &As[bb][w * 8][0]);       \
        GLD_LDS16(Ab1 + (k0), &As[bb][64 + w * 8][0]);  \
        GLD_LDS16(Bb0 + (k0), &Bs[bb][w * 8][0]);       \
        GLD_LDS16(Bb1 + (k0), &Bs[bb][64 + w * 8][0]);  \
    } while (0)

    STAGE(0, 0);
    __syncthreads();
    int cur = 0;

    for (int kt = 0; kt < 16; kt++) {
        if (kt + 1 < 16) STAGE(cur ^ 1, (kt + 1) * 64);
#pragma unroll
        for (int ks = 0; ks < 2; ks++) {
            short8v af[4], bfv[2];
            int hh = ks * 4 + lg;
            int sw = ((hh ^ (lr & 7)) * 8);
#pragma unroll
            for (int fm = 0; fm < 4; fm++)
                af[fm] = *(const short8v*)&As[cur][wm * 64 + fm * 16 + lr][sw];
#pragma unroll
            for (int fn = 0; fn < 2; fn++)
                bfv[fn] = *(const short8v*)&Bs[cur][wn * 32 + fn * 16 + lr][sw];
            __builtin_amdgcn_s_setprio(1);
#pragma unroll
            for (int fm = 0; fm < 4; fm++)
#pragma unroll
                for (int fn = 0; fn < 2; fn++)
                    acc[fm][fn] = (MODE == 1)
                        ? __builtin_amdgcn_mfma_f32_16x16x32_bf16(bfv[fn], af[fm], acc[fm][fn], 0, 0, 0)
                        : __builtin_amdgcn_mfma_f32_16x16x32_bf16(af[fm], bfv[fn], acc[fm][fn], 0, 0, 0);
            __builtin_amdgcn_s_setprio(0);
        }
        __syncthreads();   // drains stage vmcnt (next buf ready) + all reads of cur done
        cur ^= 1;
    }
#undef STAGE

    if (MODE == 0) {
        short* out = (blockIdx.z == 0) ? out0 : out1;
        float scale = (blockIdx.z == 0) ? 0.125f * 1.44269504088896f : 1.0f;
#pragma unroll
        for (int fm = 0; fm < 4; fm++)
#pragma unroll
            for (int fn = 0; fn < 2; fn++)
#pragma unroll
                for (int r = 0; r < 4; r++) {
                    int m = m0 + wm * 64 + fm * 16 + lg * 4 + r;
                    int n = n0 + wn * 32 + fn * 16 + lr;
                    float v = acc[fm][fn][r] * scale;
                    int b = m >> 11, s = m & 2047, h = n >> 6, dh = n & 63;
                    out[(((size_t)(b * 16 + h)) * 2048 + s) * 64 + dh] = f2bf(v);
                }
    } else if (MODE == 1) {
        // D is transposed: row index = n-dim, col index = m-dim
#pragma unroll
        for (int fm = 0; fm < 4; fm++)
#pragma unroll
            for (int fn = 0; fn < 2; fn++)
#pragma unroll
                for (int r = 0; r < 4; r++) {
                    int n = n0 + wn * 32 + fn * 16 + lg * 4 + r;
                    int m = m0 + wm * 64 + fm * 16 + lr;
                    int b = m >> 11, s = m & 2047, h = n >> 6, dh = n & 63;
                    out0[(((size_t)(b * 16 + h)) * 64 + dh) * 2048 + s] = f2bf(acc[fm][fn][r]);
                }
    } else {
#pragma unroll
        for (int fm = 0; fm < 4; fm++)
#pragma unroll
            for (int fn = 0; fn < 2; fn++)
#pragma unroll
                for (int r = 0; r < 4; r++) {
                    int m = m0 + wm * 64 + fm * 16 + lg * 4 + r;
                    int n = n0 + wn * 32 + fn * 16 + lr;
                    outF[(size_t)m * 1024 + n] = acc[fm][fn][r];
                }
    }
}

// ---------------- causal flash attention v4 (unchanged from R4) ----------------
__launch_bounds__(256, 2)
__global__ void k_attn(const short* __restrict__ Qb, const short* __restrict__ Kb,
                       const short* __restrict__ Vtb, short* __restrict__ Ob) {
    __shared__ short K_lds[2][64][64];
    __shared__ short V_lds[2][64][64];
    __shared__ short p_lds[4][16][72];
    int t = threadIdx.x;
    int l = t & 63, w = t >> 6;
    int lr = l & 15, lg = l >> 4;

    int L = blockIdx.y * 16 + blockIdx.x;
    int bh = (L & 7) * 4 + ((L >> 3) & 3);
    int p = L >> 5;

    const short* Qp = Qb + (size_t)bh * 2048 * 64;
    const short* Kp = Kb + (size_t)bh * 2048 * 64;
    const short* Vp = Vtb + (size_t)bh * 64 * 2048;

    int n0 = 32 - p;
    int n1 = p + 1;
    const int total = 33;

    int srow = 0, scol = 0;
    {
        // placeholders to keep naming clear
    }

    auto stage = [&](int bb, int kv0) {
#pragma unroll
        for (int i = 0; i < 2; i++) {
            int s = w * 64 + i * 256 + l;
            int row = s >> 3, cg = s & 7;
            int cs = (cg ^ (row & 7)) * 8;
            GLD_LDS16(&Kp[(size_t)(kv0 + row) * 64 + cs],
                      (short*)K_lds[bb] + (size_t)(w * 64 + i * 256) * 8);
            GLD_LDS16(&Vp[(size_t)row * 2048 + kv0 + cs],
                      (short*)V_lds[bb] + (size_t)(w * 64 + i * 256) * 8);
        }
    };

    stage(0, 0);

    int tile = 31 - p;
    int q0 = tile * 64 + w * 16;
    short8v qf0 = *(const short8v*)&Qp[(size_t)(q0 + lr) * 64 + lg * 8];
    short8v qf1 = *(const short8v*)&Qp[(size_t)(q0 + lr) * 64 + 32 + lg * 8];

    float4v o[4] = {};
    float mr[4] = {-3e38f, -3e38f, -3e38f, -3e38f};
    float lsum[4] = {0.f, 0.f, 0.f, 0.f};
    int cur = 0;
    int b = bh >> 4, h = bh & 15;

    __syncthreads();

    for (int ci = 0; ci < total; ci++) {
        bool second = ci >= n0;
        int ntile = second ? n1 : n0;
        int c = second ? ci - n0 : ci;
        int kv0 = c * 64;

        int cin = ci + 1;
        if (cin < total) {
            int kvn = (cin < n0) ? cin * 64 : (cin - n0) * 64;
            stage(cur ^ 1, kvn);
        }

        const short* Kf = (const short*)K_lds[cur];
        float4v s[4] = {};
        __builtin_amdgcn_s_setprio(1);
#pragma unroll
        for (int t4 = 0; t4 < 4; t4++) {
            int krow = t4 * 16 + lr;
            int sw = (krow & 7);
            short8v kfa = *(const short8v*)&Kf[krow * 64 + ((lg ^ sw) * 8)];
            short8v kfb = *(const short8v*)&Kf[krow * 64 + (((lg ^ 4) ^ sw) * 8)];
            s[t4] = __builtin_amdgcn_mfma_f32_16x16x32_bf16(qf0, kfa, s[t4], 0, 0, 0);
            s[t4] = __builtin_amdgcn_mfma_f32_16x16x32_bf16(qf1, kfb, s[t4], 0, 0, 0);
        }
        __builtin_amdgcn_s_setprio(0);

        if (c == ntile - 1) {
#pragma unroll
            for (int t4 = 0; t4 < 4; t4++)
#pragma unroll
                for (int r = 0; r < 4; r++) {
                    int row = q0 + lg * 4 + r;
                    if (kv0 + t4 * 16 + lr > row) s[t4][r] = -3e38f;
                }
        }

        float mx[4];
#pragma unroll
        for (int r = 0; r < 4; r++) {
            float m_ = fmaxf(fmaxf(s[0][r], s[1][r]), fmaxf(s[2][r], s[3][r]));
            m_ = fmaxf(m_, __shfl_xor(m_, 1));
            m_ = fmaxf(m_, __shfl_xor(m_, 2));
            m_ = fmaxf(m_, __shfl_xor(m_, 4));
            m_ = fmaxf(m_, __shfl_xor(m_, 8));
            mx[r] = m_;
        }
        bool ok = (mx[0] - mr[0] <= 8.f) && (mx[1] - mr[1] <= 8.f) &&
                  (mx[2] - mr[2] <= 8.f) && (mx[3] - mr[3] <= 8.f);
        if (!__all((int)ok)) {
#pragma unroll
            for (int r = 0; r < 4; r++) {
                float mnew = fmaxf(mr[r], mx[r]);
                float sc = __builtin_amdgcn_exp2f(mr[r] - mnew);
                mr[r] = mnew;
                lsum[r] *= sc;
                o[0][r] *= sc; o[1][r] *= sc; o[2][r] *= sc; o[3][r] *= sc;
            }
        }
#pragma unroll
        for (int r = 0; r < 4; r++) {
            float e0 = __builtin_amdgcn_exp2f(s[0][r] - mr[r]);
            float e1 = __builtin_amdgcn_exp2f(s[1][r] - mr[r]);
            float e2 = __builtin_amdgcn_exp2f(s[2][r] - mr[r]);
            float e3 = __builtin_amdgcn_exp2f(s[3][r] - mr[r]);
            lsum[r] += (e0 + e1) + (e2 + e3);
            p_lds[w][lg * 4 + r][lr]      = f2bf(e0);
            p_lds[w][lg * 4 + r][16 + lr] = f2bf(e1);
            p_lds[w][lg * 4 + r][32 + lr] = f2bf(e2);
            p_lds[w][lg * 4 + r][48 + lr] = f2bf(e3);
        }

        short8v pa0 = *(const short8v*)&p_lds[w][lr][lg * 8];
        short8v pa1 = *(const short8v*)&p_lds[w][lr][32 + lg * 8];

        const short* Vf = (const short*)V_lds[cur];
        __builtin_amdgcn_s_setprio(1);
#pragma unroll
        for (int dt = 0; dt < 4; dt++) {
            int vrow = dt * 16 + lr;
            int sw = (vrow & 7);
            short8v vfa = *(const short8v*)&Vf[vrow * 64 + ((lg ^ sw) * 8)];
            short8v vfb = *(const short8v*)&Vf[vrow * 64 + (((lg ^ 4) ^ sw) * 8)];
            o[dt] = __builtin_amdgcn_mfma_f32_16x16x32_bf16(pa0, vfa, o[dt], 0, 0, 0);
            o[dt] = __builtin_amdgcn_mfma_f32_16x16x32_bf16(pa1, vfb, o[dt], 0, 0, 0);
        }
        __builtin_amdgcn_s_setprio(0);

        if (c == ntile - 1) {
            float inv[4];
#pragma unroll
            for (int r = 0; r < 4; r++) {
                float ls = lsum[r];
                ls += __shfl_xor(ls, 1);
                ls += __shfl_xor(ls, 2);
                ls += __shfl_xor(ls, 4);
                ls += __shfl_xor(ls, 8);
                inv[r] = 1.0f / ls;
            }
#pragma unroll
            for (int dt = 0; dt < 4; dt++)
#pragma unroll
                for (int r = 0; r < 4; r++) {
                    int q = q0 + lg * 4 + r;
                    Ob[((size_t)(b * 2048 + q)) * 1024 + h * 64 + dt * 16 + lr] = f2bf(o[dt][r] * inv[r]);
                }
            if (!second) {
                tile = p;
                q0 = tile * 64 + w * 16;
                qf0 = *(const short8v*)&Qp[(size_t)(q0 + lr) * 64 + lg * 8];
                qf1 = *(const short8v*)&Qp[(size_t)(q0 + lr) * 64 + 32 + lg * 8];
#pragma unroll
                for (int dt = 0; dt < 4; dt++) o[dt] = float4v{0.f, 0.f, 0.f, 0.f};
#pragma unroll
                for (int r = 0; r < 4; r++) { mr[r] = -3e38f; lsum[r] = 0.f; }
            }
        }

        __syncthreads();
        cur ^= 1;
    }
}

extern "C" void kernel_launch(void* const* d_in, const int* in_sizes, int n_in,
                              void* d_out, int out_size, void* d_ws, size_t ws_size,
                              hipStream_t stream) {
    const float* x  = (const float*)d_in[0];
    const float* Wq = (const float*)d_in[1];
    const float* Wk = (const float*)d_in[2];
    const float* Wv = (const float*)d_in[3];
    const float* Wo = (const float*)d_in[4];
    float* out = (float*)d_out;

    char* ws = (char*)d_ws;
    short* xb  = (short*)(ws);                 // [4096][1024] bf16       8 MB
    short* Wtb = (short*)(ws + 8388608);       // 4 x [1024 n][1024 k]    8 MB
    short* Qb  = (short*)(ws + 16777216);      // [B,H,S,Dh] (pre-scaled) 8 MB
    short* Kb  = (short*)(ws + 25165824);      // [B,H,S,Dh]              8 MB
    short* Vtb = (short*)(ws + 33554432);      // [B,H,Dh,S]              8 MB
    short* Ob  = (short*)(ws + 41943040);      // [B,S,D] bf16            8 MB

    k_cvt_x<<<4096, 256, 0, stream>>>(x, xb);
    k_transpose<<<dim3(32, 32, 4), dim3(32, 8), 0, stream>>>(Wq, Wk, Wv, Wo, Wtb);
    k_gemm2<0><<<dim3(32, 8, 2), 512, 0, stream>>>(xb, Wtb, Qb, Kb, nullptr);
    k_gemm2<1><<<dim3(32, 8), 512, 0, stream>>>(xb, Wtb + 2 * 1048576, Vtb, nullptr, nullptr);
    k_attn<<<dim3(16, 32), 256, 0, stream>>>(Qb, Kb, Vtb, Ob);
    k_gemm2<2><<<dim3(32, 8), 512, 0, stream>>>(Ob, Wtb + 3 * 1048576, nullptr, nullptr, out);
}